// Round 2
// baseline (402.991 us; speedup 1.0000x reference)
//
#include <hip/hip_runtime.h>
#include <hip/hip_bf16.h>

// Problem constants (match reference)
#define BB      64
#define DD      256
#define NROWS   200000
#define TEMP_INV 20.0f      // 1/0.05
#define MOM     0.2f
#define OMOM    0.8f
#define EPSN    1e-12f

#define TILE_R  16
#define NTILES  (NROWS / TILE_R)   // 12500 exactly
#define GRID_B  1024

__device__ __forceinline__ float wave_allreduce_sum(float v) {
#pragma unroll
    for (int m = 32; m >= 1; m >>= 1) v += __shfl_xor(v, m, 64);
    return v;
}

// Kernel A: normalize inputs -> xq (layout [d/4][b] as float4), zero gsum and loss.
__global__ void normalize_kernel(const float* __restrict__ inputs,
                                 float* __restrict__ xq,
                                 float* __restrict__ gsum,
                                 float* __restrict__ out) {
    int b = blockIdx.x, l = threadIdx.x;   // 64 blocks x 64 threads
    const float4* in4 = (const float4*)inputs;
    float4 v = in4[b * 64 + l];            // lane l holds d = 4l..4l+3
    float ss = v.x * v.x + v.y * v.y + v.z * v.z + v.w * v.w;
    ss = wave_allreduce_sum(ss);
    float inv = 1.0f / fmaxf(sqrtf(ss), EPSN);
    float4 x = make_float4(v.x * inv, v.y * inv, v.z * inv, v.w * inv);
    ((float4*)xq)[l * 64 + b] = x;         // transposed chunk layout for kernel B
    if (l == 0) gsum[b] = 0.0f;
    if (b == 0 && l == 0) out[0] = 0.0f;
}

// Kernel B: streaming pass over features.
//  - copies each row to out+1 (dword-coalesced)
//  - accumulates gsum[b] = sum_n exp(dot(x_b, f_n)/TEMP - 20)
// Mapping: lane l <-> b, wave w <-> d-quarter [64w, 64w+64). x in registers.
__global__ __launch_bounds__(256, 3) void bank_kernel(
    const float* __restrict__ feat,
    const float* __restrict__ xq,
    float* __restrict__ out,
    float* __restrict__ gsum) {
    __shared__ float4 fld[TILE_R * 64];       // 16 KB feature tile
    __shared__ float  part[4][TILE_R][BB];    // 16 KB partial dots
    __shared__ float  fin[4][BB];             // 1 KB final reduce

    int tid = threadIdx.x;
    int w = tid >> 6, l = tid & 63;

    const float4* xq4 = (const float4*)xq;
    float4 xr[16];
#pragma unroll
    for (int j = 0; j < 16; ++j) xr[j] = xq4[(w * 16 + j) * 64 + l];

    const float4* feat4 = (const float4*)feat;
    float* outF = out + 1;
    const float* fldF = (const float*)fld;
    float psum = 0.0f;

    for (int tile = blockIdx.x; tile < NTILES; tile += (int)gridDim.x) {
        int base4 = tile * (TILE_R * 64);
        float4 v0 = feat4[base4 + tid];
        float4 v1 = feat4[base4 + tid + 256];
        float4 v2 = feat4[base4 + tid + 512];
        float4 v3 = feat4[base4 + tid + 768];
        fld[tid]       = v0;
        fld[tid + 256] = v1;
        fld[tid + 512] = v2;
        fld[tid + 768] = v3;
        __syncthreads();   // B1: tile staged

        // Fused copy: lane-consecutive dwords (out+1 is 4B-misaligned for float4)
        int base = tile * (TILE_R * DD);
#pragma unroll
        for (int k = 0; k < 16; ++k)
            outF[base + tid + 256 * k] = fldF[tid + 256 * k];

        // Dot products: lane owns b=l, wave owns d-quarter
        float p[TILE_R];
#pragma unroll
        for (int r = 0; r < TILE_R; ++r) p[r] = 0.0f;
#pragma unroll
        for (int j = 0; j < 16; ++j) {
            float4 xj = xr[j];
#pragma unroll
            for (int r = 0; r < TILE_R; ++r) {
                float4 f = fld[r * 64 + w * 16 + j];   // uniform addr -> broadcast
                p[r] = fmaf(xj.x, f.x, p[r]);
                p[r] = fmaf(xj.y, f.y, p[r]);
                p[r] = fmaf(xj.z, f.z, p[r]);
                p[r] = fmaf(xj.w, f.w, p[r]);
            }
        }
#pragma unroll
        for (int r = 0; r < TILE_R; ++r) part[w][r][l] = p[r];
        __syncthreads();   // B2: partials ready

        // Reduce across waves; thread (w,l) handles b=l, rows w*4..w*4+3
#pragma unroll
        for (int i = 0; i < 4; ++i) {
            int r = (w << 2) | i;
            float dsum = part[0][r][l] + part[1][r][l]
                       + part[2][r][l] + part[3][r][l];
            psum += __expf(fmaf(dsum, TEMP_INV, -20.0f));
        }
        __syncthreads();   // B3: safe to restage
    }

    fin[w][l] = psum;
    __syncthreads();
    if (tid < BB) {
        float s = fin[0][tid] + fin[1][tid] + fin[2][tid] + fin[3][tid];
        atomicAdd(&gsum[tid], s);
    }
}

// Kernel C: per-sample CE loss + momentum update of target rows.
__global__ void update_kernel(const float* __restrict__ inputs,
                              const float* __restrict__ scores,
                              const float* __restrict__ feat,
                              const int* __restrict__ targets,
                              const float* __restrict__ gsum,
                              float* __restrict__ out) {
    int b = blockIdx.x, l = threadIdx.x;   // 64 blocks x 64 threads
    const float4* in4 = (const float4*)inputs;
    float4 v = in4[b * 64 + l];
    float ss = wave_allreduce_sum(v.x * v.x + v.y * v.y + v.z * v.z + v.w * v.w);
    float inv = 1.0f / fmaxf(sqrtf(ss), EPSN);
    float4 x = make_float4(v.x * inv, v.y * inv, v.z * inv, v.w * inv);

    int t = targets[b];
    const float4* feat4 = (const float4*)feat;
    float4 old = feat4[t * 64 + l];

    float dt = wave_allreduce_sum(x.x * old.x + x.y * old.y +
                                  x.z * old.z + x.w * old.w);
    float sc = scores[b];
    float c = OMOM * sc;
    float4 u = make_float4(MOM * old.x + c * x.x,
                           MOM * old.y + c * x.y,
                           MOM * old.z + c * x.z,
                           MOM * old.w + c * x.w);
    float us = wave_allreduce_sum(u.x * u.x + u.y * u.y + u.z * u.z + u.w * u.w);
    float uinv = 1.0f / fmaxf(sqrtf(us), EPSN);
    u.x *= uinv; u.y *= uinv; u.z *= uinv; u.w *= uinv;

    float* outF = out + 1;
    int bi = t * DD + 4 * l;
    outF[bi]     = u.x;
    outF[bi + 1] = u.y;
    outF[bi + 2] = u.z;
    outF[bi + 3] = u.w;

    if (l == 0) {
        float lse = 20.0f + logf(gsum[b]);       // logsumexp with fixed shift
        float ce  = lse - dt * TEMP_INV;         // -log p[target]
        atomicAdd(&out[0], sc * ce);
    }
}

extern "C" void kernel_launch(void* const* d_in, const int* in_sizes, int n_in,
                              void* d_out, int out_size, void* d_ws, size_t ws_size,
                              hipStream_t stream) {
    const float* inputs  = (const float*)d_in[0];
    const float* scores  = (const float*)d_in[1];
    const float* feat    = (const float*)d_in[2];
    const int*   targets = (const int*)d_in[3];
    float* out = (float*)d_out;

    float* xq   = (float*)d_ws;        // 16384 floats (64 KB)
    float* gsum = xq + 16384;          // 64 floats

    normalize_kernel<<<64, 64, 0, stream>>>(inputs, xq, gsum, out);
    bank_kernel<<<GRID_B, 256, 0, stream>>>(feat, xq, out, gsum);
    update_kernel<<<64, 64, 0, stream>>>(inputs, scores, feat, targets, gsum, out);
}

// Round 3
// 357.062 us; speedup vs baseline: 1.1286x; 1.1286x over previous
//
#include <hip/hip_runtime.h>
#include <hip/hip_bf16.h>

// Problem constants (match reference)
#define BB      64
#define DD      256
#define NROWS   200000
#define TEMP_INV 20.0f      // 1/0.05
#define MOM     0.2f
#define OMOM    0.8f
#define EPSN    1e-12f

#define TILE_R  16
#define NTILES  (NROWS / TILE_R)   // 12500 exactly
#define GRID_B  1024

typedef __attribute__((ext_vector_type(8))) short  short8;   // 8 bf16 (4 VGPR)
typedef __attribute__((ext_vector_type(4))) float  f32x4;    // MFMA acc

__device__ __forceinline__ float wave_allreduce_sum(float v) {
#pragma unroll
    for (int m = 32; m >= 1; m >>= 1) v += __shfl_xor(v, m, 64);
    return v;
}

// fp32 -> bf16, round-to-nearest-even
__device__ __forceinline__ ushort f2bf(float f) {
    uint u = __float_as_uint(f);
    u = (u + 0x7FFFu + ((u >> 16) & 1u)) >> 16;
    return (ushort)u;
}

// Kernel A: normalize inputs; emit bf16 A-fragments for the MFMA GEMM.
// Fragment layout for mfma_f32_16x16x32_bf16, A[16x32] per (w=b>>4, kc):
//   lane l holds A[row=l&15][k = 8*(l>>4)+j], j=0..7  (k global d = kc*32+k)
// Stored flat: xf[(w*8+kc)*64 + l] as 16B (short8).
__global__ void normalize_kernel(const float* __restrict__ inputs,
                                 uint4* __restrict__ xf,
                                 float* __restrict__ gsum,
                                 float* __restrict__ out) {
    __shared__ float xs[DD];
    int b = blockIdx.x, l = threadIdx.x;   // 64 blocks x 64 threads
    const float4* in4 = (const float4*)inputs;
    float4 v = in4[b * 64 + l];            // lane l holds d = 4l..4l+3
    float ss = wave_allreduce_sum(v.x * v.x + v.y * v.y + v.z * v.z + v.w * v.w);
    float inv = 1.0f / fmaxf(sqrtf(ss), EPSN);
    xs[4 * l + 0] = v.x * inv;
    xs[4 * l + 1] = v.y * inv;
    xs[4 * l + 2] = v.z * inv;
    xs[4 * l + 3] = v.w * inv;
    __syncthreads();
    if (l < 32) {                           // 32 fragments-of-8 per row b
        int kc = l >> 2, g = l & 3;
        int d0 = kc * 32 + g * 8;
        ushort h[8];
#pragma unroll
        for (int j = 0; j < 8; ++j) h[j] = f2bf(xs[d0 + j]);
        uint4 p;
        p.x = (uint)h[0] | ((uint)h[1] << 16);
        p.y = (uint)h[2] | ((uint)h[3] << 16);
        p.z = (uint)h[4] | ((uint)h[5] << 16);
        p.w = (uint)h[6] | ((uint)h[7] << 16);
        xf[(b >> 4) * 512 + kc * 64 + g * 16 + (b & 15)] = p;
    }
    if (l == 0) gsum[b] = 0.0f;
    if (b == 0 && l == 0) out[0] = 0.0f;
}

// Kernel B: streaming pass over features.
//  - copies each row to out+1 exactly (fp32, dword-coalesced via LDS)
//  - bf16 MFMA logits: gsum[b] += sum_n exp(dot(x_b,f_n)/TEMP - 20)
// Wave w owns b-block [16w,16w+16); tile = 16 feature rows.
__global__ __launch_bounds__(256, 4) void bank_kernel(
    const float* __restrict__ feat,
    const uint4* __restrict__ xf,
    float* __restrict__ out,
    float* __restrict__ gsum) {
    __shared__ float4 fld[TILE_R * 64];        // 16 KB fp32 tile (exact copy)
    __shared__ ushort bft[TILE_R * 256];       // 8 KB bf16 tile (XOR-swizzled)
    __shared__ float  fin[4][64][4];           // 4 KB expsum partials

    int tid = threadIdx.x;
    int w = tid >> 6, l = tid & 63;
    int n16 = l & 15, g = l >> 4;

    // A-fragments: x for b = w*16 + (l&15), held in registers for the whole pass
    short8 afrag[8];
    const short8* xf8 = (const short8*)xf;
#pragma unroll
    for (int kc = 0; kc < 8; ++kc) afrag[kc] = xf8[(w * 8 + kc) * 64 + l];

    // B-fragment swizzled byte offsets (row n16, d-bytes kc*64+g*16, 16B each)
    int boff[8];
#pragma unroll
    for (int kc = 0; kc < 8; ++kc)
        boff[kc] = n16 * 512 + ((kc * 64 + g * 16) ^ ((n16 & 7) << 4));

    const float4* feat4 = (const float4*)feat;
    float* outF = out + 1;
    const float* fldF = (const float*)fld;
    float psum[4] = {0.f, 0.f, 0.f, 0.f};

    for (int tile = blockIdx.x; tile < NTILES; tile += (int)gridDim.x) {
        int base4 = tile * (TILE_R * 64);
#pragma unroll
        for (int k = 0; k < 4; ++k) {
            int flat = tid + 256 * k;          // float4 index in tile
            float4 v = feat4[base4 + flat];
            fld[flat] = v;                     // fp32 for exact copy
            // bf16 swizzled store: row n, 8B chunk c
            int n = flat >> 6, c = flat & 63;
            uint2 pk;
            pk.x = (uint)f2bf(v.x) | ((uint)f2bf(v.y) << 16);
            pk.y = (uint)f2bf(v.z) | ((uint)f2bf(v.w) << 16);
            *(uint2*)((char*)bft + n * 512 + ((c * 8) ^ ((n & 7) << 4))) = pk;
        }
        __syncthreads();   // tile staged

        // Exact fp32 copy (out+1 is 4B-misaligned for float4 -> dense dwords)
        int base = tile * (TILE_R * DD);
#pragma unroll
        for (int k = 0; k < 16; ++k)
            outF[base + tid + 256 * k] = fldF[tid + 256 * k];

        // MFMA: D[16b x 16n] over K=256 in 8 chained steps
        f32x4 acc = {0.f, 0.f, 0.f, 0.f};
#pragma unroll
        for (int kc = 0; kc < 8; ++kc) {
            short8 bfr = *(const short8*)((const char*)bft + boff[kc]);
            acc = __builtin_amdgcn_mfma_f32_16x16x32_bf16(afrag[kc], bfr, acc, 0, 0, 0);
        }
        // lane holds D[b = w*16 + g*4 + r][n = tile*16 + n16]
#pragma unroll
        for (int r = 0; r < 4; ++r)
            psum[r] += __expf(fmaf(acc[r], TEMP_INV, -20.0f));
        __syncthreads();   // safe to restage
    }

#pragma unroll
    for (int r = 0; r < 4; ++r) fin[w][l][r] = psum[r];
    __syncthreads();
    if (tid < BB) {        // b = tid: sum over the 16 lanes (n16) holding it
        int b = tid, bw = b >> 4, grp = (b >> 2) & 3, reg = b & 3;
        float s = 0.f;
#pragma unroll
        for (int c = 0; c < 16; ++c) s += fin[bw][grp * 16 + c][reg];
        atomicAdd(&gsum[b], s);
    }
}

// Kernel C: per-sample CE loss + momentum update of target rows (fp32 exact).
__global__ void update_kernel(const float* __restrict__ inputs,
                              const float* __restrict__ scores,
                              const float* __restrict__ feat,
                              const int* __restrict__ targets,
                              const float* __restrict__ gsum,
                              float* __restrict__ out) {
    int b = blockIdx.x, l = threadIdx.x;   // 64 blocks x 64 threads
    const float4* in4 = (const float4*)inputs;
    float4 v = in4[b * 64 + l];
    float ss = wave_allreduce_sum(v.x * v.x + v.y * v.y + v.z * v.z + v.w * v.w);
    float inv = 1.0f / fmaxf(sqrtf(ss), EPSN);
    float4 x = make_float4(v.x * inv, v.y * inv, v.z * inv, v.w * inv);

    int t = targets[b];
    const float4* feat4 = (const float4*)feat;
    float4 old = feat4[t * 64 + l];

    float dt = wave_allreduce_sum(x.x * old.x + x.y * old.y +
                                  x.z * old.z + x.w * old.w);
    float sc = scores[b];
    float c = OMOM * sc;
    float4 u = make_float4(MOM * old.x + c * x.x,
                           MOM * old.y + c * x.y,
                           MOM * old.z + c * x.z,
                           MOM * old.w + c * x.w);
    float us = wave_allreduce_sum(u.x * u.x + u.y * u.y + u.z * u.z + u.w * u.w);
    float uinv = 1.0f / fmaxf(sqrtf(us), EPSN);
    u.x *= uinv; u.y *= uinv; u.z *= uinv; u.w *= uinv;

    float* outF = out + 1;
    int bi = t * DD + 4 * l;
    outF[bi]     = u.x;
    outF[bi + 1] = u.y;
    outF[bi + 2] = u.z;
    outF[bi + 3] = u.w;

    if (l == 0) {
        float lse = 20.0f + logf(gsum[b]);       // logsumexp with fixed shift
        float ce  = lse - dt * TEMP_INV;         // -log p[target]
        atomicAdd(&out[0], sc * ce);
    }
}

extern "C" void kernel_launch(void* const* d_in, const int* in_sizes, int n_in,
                              void* d_out, int out_size, void* d_ws, size_t ws_size,
                              hipStream_t stream) {
    const float* inputs  = (const float*)d_in[0];
    const float* scores  = (const float*)d_in[1];
    const float* feat    = (const float*)d_in[2];
    const int*   targets = (const int*)d_in[3];
    float* out = (float*)d_out;

    uint4* xf   = (uint4*)d_ws;                        // 2048 x 16B = 32 KB
    float* gsum = (float*)((char*)d_ws + 32768);       // 64 floats

    normalize_kernel<<<64, 64, 0, stream>>>(inputs, xf, gsum, out);
    bank_kernel<<<GRID_B, 256, 0, stream>>>(feat, xf, out, gsum);
    update_kernel<<<64, 64, 0, stream>>>(inputs, scores, feat, targets, gsum, out);
}